// Round 10
// baseline (347.307 us; speedup 1.0000x reference)
//
#include <hip/hip_runtime.h>
#include <hip/hip_bf16.h>
#include <math.h>

#define D_MODEL 1024
#define SEQ     2048
#define NHEAD   16

typedef __attribute__((ext_vector_type(8))) short bf16x8;
typedef __attribute__((ext_vector_type(8))) unsigned short u16x8;
typedef __attribute__((ext_vector_type(4))) float f32x4;
typedef const __attribute__((address_space(1))) unsigned int* gas_u32p;
typedef __attribute__((address_space(3))) unsigned int* las_u32p;

__device__ __forceinline__ void load16(const void* g, void* l) {
  __builtin_amdgcn_global_load_lds((gas_u32p)g, (las_u32p)l, 16, 0, 0);
}

__device__ __forceinline__ unsigned short f2bf(float f) {
  __hip_bfloat16 h = __float2bfloat16(f);
  return *(unsigned short*)&h;
}
__device__ __forceinline__ float bf2f(unsigned short u) {
  return __uint_as_float((unsigned)u << 16);
}

// ---------------------------------------------------------------------------
// fp32 -> bf16 for q,k,v in one launch (blockIdx.y selects tensor)
// ---------------------------------------------------------------------------
__global__ __launch_bounds__(256) void cvt3_bf16(
    const float4* __restrict__ q, const float4* __restrict__ k,
    const float4* __restrict__ v, ushort4* __restrict__ qo,
    ushort4* __restrict__ ko, ushort4* __restrict__ vo) {
  const int i = blockIdx.x * 256 + threadIdx.x;
  const float4* in = (blockIdx.y == 0) ? q : (blockIdx.y == 1) ? k : v;
  ushort4* out = (blockIdx.y == 0) ? qo : (blockIdx.y == 1) ? ko : vo;
  const float4 f = in[i];
  ushort4 u;
  u.x = f2bf(f.x); u.y = f2bf(f.y); u.z = f2bf(f.z); u.w = f2bf(f.w);
  out[i] = u;
}

// ---------------------------------------------------------------------------
// 4 x (W [1024 k][1024 n] fp32 -> Wt bf16 [n][k]), blockIdx.z selects
// ---------------------------------------------------------------------------
__global__ __launch_bounds__(256) void wt_cvt4(
    const float* __restrict__ W0, const float* __restrict__ W1,
    const float* __restrict__ W2, const float* __restrict__ W3,
    unsigned short* __restrict__ O0, unsigned short* __restrict__ O1,
    unsigned short* __restrict__ O2, unsigned short* __restrict__ O3) {
  __shared__ float t[64][65];
  const int z = blockIdx.z;
  const float* W = (z == 0) ? W0 : (z == 1) ? W1 : (z == 2) ? W2 : W3;
  unsigned short* Wh = (z == 0) ? O0 : (z == 1) ? O1 : (z == 2) ? O2 : O3;
  const int tid = threadIdx.x;
  const int k0 = blockIdx.y * 64, n0 = blockIdx.x * 64;
  #pragma unroll
  for (int it = 0; it < 4; ++it) {
    const int r = it * 16 + (tid >> 4), c4 = (tid & 15) * 4;
    const float4 f = *(const float4*)&W[(size_t)(k0 + r) * D_MODEL + n0 + c4];
    t[r][c4 + 0] = f.x; t[r][c4 + 1] = f.y;
    t[r][c4 + 2] = f.z; t[r][c4 + 3] = f.w;
  }
  __syncthreads();
  #pragma unroll
  for (int it = 0; it < 4; ++it) {
    const int n = it * 16 + (tid >> 4), k4 = (tid & 15) * 4;
    ushort4 uh;
    uh.x = f2bf(t[k4 + 0][n]); uh.y = f2bf(t[k4 + 1][n]);
    uh.z = f2bf(t[k4 + 2][n]); uh.w = f2bf(t[k4 + 3][n]);
    *(ushort4*)&Wh[(size_t)(n0 + n) * D_MODEL + k0 + k4] = uh;
  }
}

// ---------------------------------------------------------------------------
// Fused Q/K/V projections. 128x128 tile, BK=64, grid 768 (validated r7-r9).
// Q pre-scaled by 0.125*log2(e).
// ---------------------------------------------------------------------------
__global__ __launch_bounds__(512, 4) void gemm_qkv(
    const unsigned short* __restrict__ qx, const unsigned short* __restrict__ kx,
    const unsigned short* __restrict__ vx,
    const unsigned short* __restrict__ Wqt, const unsigned short* __restrict__ Wkt,
    const unsigned short* __restrict__ Wvt,
    const float* __restrict__ bq, const float* __restrict__ bk,
    const float* __restrict__ bv,
    unsigned short* __restrict__ Qo, unsigned short* __restrict__ Ko,
    unsigned short* __restrict__ Vto) {
  __shared__ char lds[65536];
  const int tid = threadIdx.x;
  const int lane = tid & 63, wid = tid >> 6;
  const int r16 = lane & 15, g = lane >> 4;
  const int bid = blockIdx.x;
  const int orig = (bid & 7) * 96 + (bid >> 3);
  const int which = orig >> 8;
  const int sub = orig & 255;
  const int bm = sub >> 3, bn = sub & 7;
  const int row0 = bm * 128, col0 = bn * 128;
  const int wm = wid >> 2, wn = wid & 3;

  const unsigned short* A = (which == 0) ? qx : (which == 1) ? kx : vx;
  const unsigned short* W = (which == 0) ? Wqt : (which == 1) ? Wkt : Wvt;
  const float* bias = (which == 0) ? bq : (which == 1) ? bk : bv;

  const unsigned short* Ag = A + (size_t)row0 * D_MODEL;
  const unsigned short* Bg = W + (size_t)col0 * D_MODEL;

  auto stage = [&](int buf, int k0) {
    char* base = lds + buf * 32768;
    #pragma unroll
    for (int c = 0; c < 2; ++c) {
      const int idx = c * 512 + tid;
      const int r = idx >> 3, ch = idx & 7;
      const size_t off = (size_t)r * D_MODEL + k0 + ((ch ^ (r & 7)) << 3);
      load16(Ag + off, base + idx * 16);
      load16(Bg + off, base + 16384 + idx * 16);
    }
  };

  stage(0, 0);
  f32x4 acc[4][2] = {};

  for (int s = 0; s < 16; ++s) {
    __syncthreads();
    if (s < 15) stage((s + 1) & 1, (s + 1) * 64);
    const char* base = lds + (s & 1) * 32768;
    #pragma unroll
    for (int kk = 0; kk < 2; ++kk) {
      bf16x8 a[4], b[2];
      #pragma unroll
      for (int mi = 0; mi < 4; ++mi) {
        const int r = wm * 64 + mi * 16 + r16;
        a[mi] = *(const bf16x8*)(base + r * 128 + (((g + kk * 4) ^ (r & 7)) << 4));
      }
      #pragma unroll
      for (int ni = 0; ni < 2; ++ni) {
        const int r = wn * 32 + ni * 16 + r16;
        b[ni] = *(const bf16x8*)(base + 16384 + r * 128 +
                                 (((g + kk * 4) ^ (r & 7)) << 4));
      }
      #pragma unroll
      for (int mi = 0; mi < 4; ++mi)
        #pragma unroll
        for (int ni = 0; ni < 2; ++ni)
          acc[mi][ni] = __builtin_amdgcn_mfma_f32_16x16x32_bf16(
              a[mi], b[ni], acc[mi][ni], 0, 0, 0);
    }
  }

  if (which < 2) {
    unsigned short* C = (which == 0) ? Qo : Ko;
    const float scale = (which == 0) ? 0.1803368802f : 1.0f;
    #pragma unroll
    for (int mi = 0; mi < 4; ++mi)
      #pragma unroll
      for (int ni = 0; ni < 2; ++ni) {
        const int col = col0 + wn * 32 + ni * 16 + r16;
        const float bb = bias[col];
        const int rowb = row0 + wm * 64 + mi * 16 + g * 4;
        #pragma unroll
        for (int j = 0; j < 4; ++j)
          C[(size_t)(rowb + j) * D_MODEL + col] =
              f2bf((acc[mi][ni][j] + bb) * scale);
      }
  } else {
    #pragma unroll
    for (int mi = 0; mi < 4; ++mi)
      #pragma unroll
      for (int ni = 0; ni < 2; ++ni) {
        const int col = col0 + wn * 32 + ni * 16 + r16;
        const int hh = col >> 6, dd = col & 63;
        const float bb = bias[col];
        const int rowb = row0 + wm * 64 + mi * 16 + g * 4;
        const int b_ = rowb >> 11, tt = rowb & 2047;
        ushort4 u;
        u.x = f2bf(acc[mi][ni][0] + bb);
        u.y = f2bf(acc[mi][ni][1] + bb);
        u.z = f2bf(acc[mi][ni][2] + bb);
        u.w = f2bf(acc[mi][ni][3] + bb);
        *(ushort4*)&Vto[((size_t)((b_ * NHEAD + hh) * 64 + dd)) * SEQ + tt] = u;
      }
  }
}

// ---------------------------------------------------------------------------
// Final GEMM: out = Oh @ Wh + bias, fp32. 64x128 tile, BK=64, grid 512
// (2-3 blocks/CU — fixes round-8/9's 1-block/CU occupancy mistake).
// ---------------------------------------------------------------------------
__global__ __launch_bounds__(512, 4) void gemm_fin64(
    const unsigned short* __restrict__ A, const unsigned short* __restrict__ B,
    const float* __restrict__ bias, float* __restrict__ O) {
  __shared__ char lds[49152];                 // 2 x (8K A + 16K B)
  const int tid = threadIdx.x;
  const int lane = tid & 63, wid = tid >> 6;
  const int r16 = lane & 15, g = lane >> 4;
  const int bid = blockIdx.x;
  const int orig = (bid & 7) * 64 + (bid >> 3);   // XCD swizzle (512%8==0)
  const int bm = orig >> 3, bn = orig & 7;
  const int row0 = bm * 64, col0 = bn * 128;
  const int wm = wid >> 2, wn = wid & 3;          // 2(m) x 4(n)

  const unsigned short* Ag = A + (size_t)row0 * D_MODEL;
  const unsigned short* Bg = B + (size_t)col0 * D_MODEL;

  auto stage = [&](int buf, int k0) {
    char* base = lds + buf * 24576;
    {                                          // A: 64 rows x 64 k
      const int r = tid >> 3, ch = tid & 7;
      load16(Ag + (size_t)r * D_MODEL + k0 + ((ch ^ (r & 7)) << 3),
             base + tid * 16);
    }
    #pragma unroll
    for (int c = 0; c < 2; ++c) {              // B: 128 rows x 64 k
      const int idx = c * 512 + tid;
      const int r = idx >> 3, ch = idx & 7;
      load16(Bg + (size_t)r * D_MODEL + k0 + ((ch ^ (r & 7)) << 3),
             base + 8192 + idx * 16);
    }
  };

  stage(0, 0);
  f32x4 acc[2][2] = {};

  for (int s = 0; s < 16; ++s) {
    __syncthreads();
    if (s < 15) stage((s + 1) & 1, (s + 1) * 64);
    const char* base = lds + (s & 1) * 24576;
    #pragma unroll
    for (int kk = 0; kk < 2; ++kk) {
      bf16x8 a[2], b[2];
      #pragma unroll
      for (int mi = 0; mi < 2; ++mi) {
        const int r = wm * 32 + mi * 16 + r16;
        a[mi] = *(const bf16x8*)(base + r * 128 + (((g + kk * 4) ^ (r & 7)) << 4));
      }
      #pragma unroll
      for (int ni = 0; ni < 2; ++ni) {
        const int r = wn * 32 + ni * 16 + r16;
        b[ni] = *(const bf16x8*)(base + 8192 + r * 128 +
                                 (((g + kk * 4) ^ (r & 7)) << 4));
      }
      #pragma unroll
      for (int mi = 0; mi < 2; ++mi)
        #pragma unroll
        for (int ni = 0; ni < 2; ++ni)
          acc[mi][ni] = __builtin_amdgcn_mfma_f32_16x16x32_bf16(
              a[mi], b[ni], acc[mi][ni], 0, 0, 0);
    }
  }

  #pragma unroll
  for (int mi = 0; mi < 2; ++mi)
    #pragma unroll
    for (int ni = 0; ni < 2; ++ni) {
      const int col = col0 + wn * 32 + ni * 16 + r16;
      const float bb = bias[col];
      const int rowb = row0 + wm * 32 + mi * 16 + g * 4;
      #pragma unroll
      for (int j = 0; j < 4; ++j)
        O[(size_t)(rowb + j) * D_MODEL + col] = acc[mi][ni][j] + bb;
    }
}

// ---------------------------------------------------------------------------
// Attention pass 1: rowsums. Block = (b,h, 128 q-rows), grid 512, 512 thr.
// Wave = 16 q-rows x full 64-t window -> rowsum completes with shfl only.
// K ring-4, vmcnt 2/1/0 (validated cadence). sums[bh][q] fp32 to global.
// ---------------------------------------------------------------------------
__global__ __launch_bounds__(512, 4) void attn_sums(
    const unsigned short* __restrict__ Qb,   // bf16, pre-scaled 0.125*log2e
    const unsigned short* __restrict__ Kb,   // bf16 [4096][1024]
    const int* __restrict__ mask,            // [2][2048]
    float* __restrict__ sums) {              // [32][2048] fp32
  __shared__ char lds[49152];
  char* const Qlds = lds;                    // 16 KB (128 rows x 128 B)
  char* const Kbuf = lds + 16384;            // 4 x 8192

  const int tid  = threadIdx.x;
  const int lane = tid & 63;
  const int wid  = tid >> 6;
  const int r16  = lane & 15;
  const int g    = lane >> 4;

  const int bid  = blockIdx.x;
  const int orig = (bid & 7) * 64 + (bid >> 3);    // XCD swizzle (512%8==0)
  const int bh   = orig >> 4;
  const int qblk = orig & 15;
  const int b    = bh >> 4, h = bh & 15;
  const int q0   = qblk * 128;

  const unsigned short* Kg0 = Kb + (size_t)(b * SEQ) * D_MODEL + h * 64;
  const unsigned short* Qg0 = Qb + (size_t)(b * SEQ + q0) * D_MODEL + h * 64;
  const int* mrow = mask + b * SEQ;

  const int srow = tid >> 3, sch = tid & 7;
  auto stageK = [&](int t) {
    load16((const char*)(Kg0 + (size_t)(t * 64 + srow) * D_MODEL) +
               (((sch ^ (srow & 7))) << 4),
           Kbuf + ((t & 3) << 13) + tid * 16);
  };

  // mask bits: mbits[tf] bit i -> t = i*64 + tf*16 + r16
  unsigned mbits[4] = {0, 0, 0, 0};
  #pragma unroll 4
  for (int i = 0; i < 32; ++i) {
    #pragma unroll
    for (int tf = 0; tf < 4; ++tf)
      mbits[tf] |= (mrow[i * 64 + tf * 16 + r16] ? 1u : 0u) << i;
  }
  asm volatile("s_waitcnt vmcnt(0)" ::: "memory");

  // Q stage (128 rows x 64 d), K tiles 0..2
  #pragma unroll
  for (int c = 0; c < 2; ++c) {
    const int idx = c * 512 + tid;
    const int r = idx >> 3, ch = idx & 7;
    load16((const char*)(Qg0 + (size_t)r * D_MODEL) + ((ch ^ (r & 7)) << 4),
           Qlds + idx * 16);
  }
  stageK(0); stageK(1); stageK(2);
  asm volatile("s_waitcnt vmcnt(3)\n\ts_barrier" ::: "memory");  // Q resident

  bf16x8 qa0, qa1;
  {
    const int row = wid * 16 + r16;
    const int sw = (row & 7) << 4;
    qa0 = *(const bf16x8*)(Qlds + row * 128 + ((g * 16) ^ sw));
    qa1 = *(const bf16x8*)(Qlds + row * 128 + ((g * 16 + 64) ^ sw));
  }

  float rs[4] = {0.f, 0.f, 0.f, 0.f};
  for (int i = 0; i < 32; ++i) {
    if (i < 30)
      asm volatile("s_waitcnt vmcnt(2)\n\ts_barrier" ::: "memory");
    else if (i == 30)
      asm volatile("s_waitcnt vmcnt(1)\n\ts_barrier" ::: "memory");
    else
      asm volatile("s_waitcnt vmcnt(0)\n\ts_barrier" ::: "memory");
    if (i + 3 < 32) stageK(i + 3);
    const char* Kt = Kbuf + ((i & 3) << 13);
    f32x4 c[4];
    __builtin_amdgcn_s_setprio(1);
    #pragma unroll
    for (int tf = 0; tf < 4; ++tf) {
      const int krow = tf * 16 + r16;
      const int ksw = (krow & 7) << 4;
      const bf16x8 kb0 = *(const bf16x8*)(Kt + krow * 128 + ((g * 16) ^ ksw));
      const bf16x8 kb1 = *(const bf16x8*)(Kt + krow * 128 + ((g * 16 + 64) ^ ksw));
      f32x4 z = {0.f, 0.f, 0.f, 0.f};
      z = __builtin_amdgcn_mfma_f32_16x16x32_bf16(qa0, kb0, z, 0, 0, 0);
      c[tf] = __builtin_amdgcn_mfma_f32_16x16x32_bf16(qa1, kb1, z, 0, 0, 0);
    }
    __builtin_amdgcn_s_setprio(0);
    #pragma unroll
    for (int tf = 0; tf < 4; ++tf) {
      if (!((mbits[tf] >> i) & 1u)) {
        rs[0] += exp2f(c[tf][0]); rs[1] += exp2f(c[tf][1]);
        rs[2] += exp2f(c[tf][2]); rs[3] += exp2f(c[tf][3]);
      }
    }
  }

  #pragma unroll
  for (int j = 0; j < 4; ++j) {
    float v = rs[j];
    v += __shfl_xor(v, 1); v += __shfl_xor(v, 2);
    v += __shfl_xor(v, 4); v += __shfl_xor(v, 8);
    rs[j] = v;
  }
  if (r16 == 0) {
    #pragma unroll
    for (int j = 0; j < 4; ++j)
      sums[(size_t)bh * SEQ + q0 + wid * 16 + g * 4 + j] = rs[j];
  }
}

// ---------------------------------------------------------------------------
// Attention pass 2: P + PV + attn write. Block = (b,h, 128 q), grid 512.
// QK recompute -> normalized bf16 P[128][64] in LDS -> PV MFMA; attn written
// in-loop via coalesced LDS readback (4 float4/thread/iter).
// vmcnt (2 loads + 4 stores/iter, 3-deep): 4,8,12,16x27,14,12.
// LDS 81920 -> exactly 2 blocks/CU.
// ---------------------------------------------------------------------------
__global__ __launch_bounds__(512, 4) void attn_pv(
    const unsigned short* __restrict__ Qb,   // bf16, pre-scaled 0.125*log2e
    const unsigned short* __restrict__ Kb,   // bf16 [4096][1024]
    const unsigned short* __restrict__ Vt,   // bf16 [32*64][2048]
    const int* __restrict__ mask,            // [2][2048]
    const float* __restrict__ sums,          // [32][2048]
    float* __restrict__ attn,                // [32][2048][2048]
    unsigned short* __restrict__ Oh) {       // bf16 [4096][1024]
  __shared__ char lds[81920];
  char* const Kbuf = lds;                    // 4 x 8192
  char* const Vbuf = lds + 32768;            // 4 x 8192
  char* const Pt   = lds + 65536;            // 16 KB: Q staging, then P tile

  const int tid  = threadIdx.x;
  const int lane = tid & 63;
  const int wid  = tid >> 6;
  const int r16  = lane & 15;
  const int g    = lane >> 4;

  const int bid  = blockIdx.x;
  const int orig = (bid & 7) * 64 + (bid >> 3);
  const int bh   = orig >> 4;
  const int qblk = orig & 15;
  const int b    = bh >> 4, h = bh & 15;
  const int q0   = qblk * 128;

  const unsigned short* Kg0 = Kb + (size_t)(b * SEQ) * D_MODEL + h * 64;
  const unsigned short* Qg0 = Qb + (size_t)(b * SEQ + q0) * D_MODEL + h * 64;
  const unsigned short* Vg0 = Vt + (size_t)(bh * 64) * SEQ;
  const int* mrow = mask + b * SEQ;

  const int srow = tid >> 3, sch = tid & 7;
  auto stageK = [&](int t) {
    load16((const char*)(Kg0 + (size_t)(t * 64 + srow) * D_MODEL) +
               ((sch ^ (srow & 7)) << 4),
           Kbuf + ((t & 3) << 13) + tid * 16);
  };
  auto stageV = [&](int t) {
    load16((const char*)(Vg0 + (size_t)srow * SEQ + t * 64) +
               ((sch ^ (srow & 7)) << 4),
           Vbuf + ((t & 3) << 13) + tid * 16);
  };

  unsigned mbits[4] = {0, 0, 0, 0};
  #pragma unroll 4
  for (int i = 0; i < 32; ++i) {
    #pragma unroll
    for (int tf = 0; tf < 4; ++tf)
      mbits[tf] |= (mrow[i * 64 + tf * 16 + r16] ? 1u : 0u) << i;
  }
  float inv_[4];
  #pragma unroll
  for (int j = 0; j < 4; ++j)
    inv_[j] = 1.f / sums[(size_t)bh * SEQ + q0 + wid * 16 + g * 4 + j];
  asm volatile("s_waitcnt vmcnt(0)" ::: "memory");

  // Q into Pt (reused for P after frags read), K/V tiles 0..2
  #pragma unroll
  for (int c = 0; c < 2; ++c) {
    const int idx = c * 512 + tid;
    const int r = idx >> 3, ch = idx & 7;
    load16((const char*)(Qg0 + (size_t)r * D_MODEL) + ((ch ^ (r & 7)) << 4),
           Pt + idx * 16);
  }
  stageK(0); stageV(0); stageK(1); stageV(1); stageK(2); stageV(2);
  asm volatile("s_waitcnt vmcnt(6)\n\ts_barrier" ::: "memory");  // Q resident

  bf16x8 qa0, qa1;
  {
    const int row = wid * 16 + r16;
    const int sw = (row & 7) << 4;
    qa0 = *(const bf16x8*)(Pt + row * 128 + ((g * 16) ^ sw));
    qa1 = *(const bf16x8*)(Pt + row * 128 + ((g * 16 + 64) ^ sw));
  }
  asm volatile("s_waitcnt lgkmcnt(0)" ::: "memory");  // qa in regs before Pt reuse

  f32x4 o[4] = {};
  const int prow0 = wid * 16 + g * 4;        // this thread's P write rows base
  const int parow = wid * 16 + r16;          // PV A-frag row
  const int pasw  = (parow & 7) << 4;
  // readback: thread -> row tid>>2, 16 t at (tid&3)*16
  const int rbq = tid >> 2, rbc = (tid & 3) * 16;
  const int rb0 = (rbq * 128 + rbc * 2) ^ ((rbq & 7) << 4);
  const int rb1 = (rbq * 128 + rbc * 2 + 16) ^ ((rbq & 7) << 4);
  float* const aT = attn + ((size_t)bh * SEQ + q0 + rbq) * SEQ + rbc;

  for (int i = 0; i < 32; ++i) {
    if (i == 0)
      asm volatile("s_waitcnt vmcnt(4)\n\ts_barrier" ::: "memory");
    else if (i == 1)
      asm volatile("s_waitcnt vmcnt(8)\n\ts_barrier" ::: "memory");
    else if (i == 2)
      asm volatile("s_waitcnt vmcnt(12)\n\ts_barrier" ::: "memory");
    else if (i <= 29)
      asm volatile("s_waitcnt vmcnt(16)\n\ts_barrier" ::: "memory");
    else if (i == 30)
      asm volatile("s_waitcnt vmcnt(14)\n\ts_barrier" ::: "memory");
    else
      asm volatile("s_waitcnt vmcnt(12)\n\ts_barrier" ::: "memory");
    if (i + 3 < 32) { stageK(i + 3); stageV(i + 3); }

    // ---- QK^T: c[4] over 4 t-frags
    const char* Kt = Kbuf + ((i & 3) << 13);
    f32x4 c[4];
    __builtin_amdgcn_s_setprio(1);
    #pragma unroll
    for (int tf = 0; tf < 4; ++tf) {
      const int krow = tf * 16 + r16;
      const int ksw = (krow & 7) << 4;
      const bf16x8 kb0 = *(const bf16x8*)(Kt + krow * 128 + ((g * 16) ^ ksw));
      const bf16x8 kb1 = *(const bf16x8*)(Kt + krow * 128 + ((g * 16 + 64) ^ ksw));
      f32x4 z = {0.f, 0.f, 0.f, 0.f};
      z = __builtin_amdgcn_mfma_f32_16x16x32_bf16(qa0, kb0, z, 0, 0, 0);
      c[tf] = __builtin_amdgcn_mfma_f32_16x16x32_bf16(qa1, kb1, z, 0, 0, 0);
    }
    __builtin_amdgcn_s_setprio(0);

    // ---- normalized P -> LDS
    #pragma unroll
    for (int tf = 0; tf < 4; ++tf) {
      const unsigned mk = (mbits[tf] >> i) & 1u;
      const int tb = tf * 16 + r16;
      #pragma unroll
      for (int j = 0; j < 4; ++j) {
        const float p = mk ? 0.f : exp2f(c[tf][j]) * inv_[j];
        const int row = prow0 + j;
        *(unsigned short*)(Pt + ((row * 128 + tb * 2) ^ ((row & 7) << 4))) =
            f2bf(p);
      }
    }

    asm volatile("s_waitcnt lgkmcnt(0)\n\ts_barrier" ::: "memory");

    // ---- PV: o[dt] over 4 d-frags
    const char* Vtl = Vbuf + ((i & 3) << 13);
    const bf16x8 pa0 = *(const bf16x8*)(Pt + parow * 128 + ((g * 16) ^ pasw));
    const bf16x8 pa1 = *(const bf16x8*)(Pt + parow * 128 + ((g * 16 + 64) ^ pasw));
    __builtin_amdgcn_s_setprio(1);
    #pragma unroll
    for (int dt = 0; dt < 4; ++dt) {
      const int vrow = dt * 16 + r16;
      const int vsw = (vrow & 7) << 4;
      const bf16x8 vb0 = *(const bf16x8*)(Vtl + vrow * 128 + ((g * 16) ^ vsw));
      const bf16x8 vb1 = *(const bf16x8*)(Vtl + vrow * 128 + ((g * 16 + 64) ^ vsw));
      o[dt] = __builtin_amdgcn_mfma_f32_16x16x32_bf16(pa0, vb0, o[dt], 0, 0, 0);
      o[dt] = __builtin_amdgcn_mfma_f32_16x16x32_bf16(pa1, vb1, o[dt], 0, 0, 0);
    }
    __builtin_amdgcn_s_setprio(0);

    // ---- coalesced attn write (readback 32B -> 4 float4 stores)
    {
      const u16x8 pvA = *(const u16x8*)(Pt + rb0);
      const u16x8 pvB = *(const u16x8*)(Pt + rb1);
      float4 w0, w1, w2, w3;
      w0.x = bf2f(pvA[0]); w0.y = bf2f(pvA[1]); w0.z = bf2f(pvA[2]); w0.w = bf2f(pvA[3]);
      w1.x = bf2f(pvA[4]); w1.y = bf2f(pvA[5]); w1.z = bf2f(pvA[6]); w1.w = bf2f(pvA[7]);
      w2.x = bf2f(pvB[0]); w2.y = bf2f(pvB[1]); w2.z = bf2f(pvB[2]); w2.w = bf2f(pvB[3]);
      w3.x = bf2f(pvB[4]); w3.y = bf2f(pvB[5]); w3.z = bf2f(pvB[6]); w3.w = bf2f(pvB[7]);
      float* dst = aT + (size_t)i * 64;
      *(float4*)(dst + 0)  = w0;
      *(float4*)(dst + 4)  = w1;
      *(float4*)(dst + 8)  = w2;
      *(float4*)(dst + 12) = w3;
    }
  }

  // ---- O epilogue (normalized), bf16
  #pragma unroll
  for (int dt = 0; dt < 4; ++dt)
    #pragma unroll
    for (int j = 0; j < 4; ++j) {
      const size_t idx = (size_t)(b * SEQ + q0 + wid * 16 + g * 4 + j) * D_MODEL
                         + h * 64 + dt * 16 + r16;
      Oh[idx] = f2bf(o[dt][j]);
    }
}

// ---------------------------------------------------------------------------
extern "C" void kernel_launch(void* const* d_in, const int* in_sizes, int n_in,
                              void* d_out, int out_size, void* d_ws, size_t ws_size,
                              hipStream_t stream) {
  const float* v    = (const float*)d_in[0];
  const float* k    = (const float*)d_in[1];
  const float* q    = (const float*)d_in[2];
  const int*   mask = (const int*)  d_in[3];
  const float* Wq   = (const float*)d_in[4];
  const float* bq   = (const float*)d_in[5];
  const float* Wk   = (const float*)d_in[6];
  const float* bk   = (const float*)d_in[7];
  const float* Wv   = (const float*)d_in[8];
  const float* bv   = (const float*)d_in[9];
  const float* Wo   = (const float*)d_in[10];
  const float* bo   = (const float*)d_in[11];

  const size_t NTOK = (size_t)2 * SEQ;            // 4096 tokens
  const size_t TOKF = NTOK * D_MODEL;             // 4,194,304 elements
  const size_t WSZ  = (size_t)D_MODEL * D_MODEL;  // 1,048,576
  float* out  = (float*)d_out;
  float* attn = out + TOKF;

  unsigned short* qx   = (unsigned short*)d_ws;   // bf16 inputs
  unsigned short* kx   = qx + TOKF;
  unsigned short* vx   = kx + TOKF;
  unsigned short* Qbf  = vx + TOKF;               // projections
  unsigned short* Kbf  = Qbf + TOKF;
  unsigned short* Vtb  = Kbf + TOKF;
  unsigned short* Ohb  = Vtb + TOKF;              // attn O (bf16)
  unsigned short* Wqt  = Ohb + TOKF;              // transposed bf16 weights
  unsigned short* Wkt  = Wqt + WSZ;
  unsigned short* Wvt  = Wkt + WSZ;
  unsigned short* Woth = Wvt + WSZ;
  float*          sums = (float*)(Woth + WSZ);    // [32][2048] rowsums

  const int cvtg = (int)(TOKF / 4 / 256);         // 4096 blocks
  cvt3_bf16<<<dim3(cvtg, 3), 256, 0, stream>>>(
      (const float4*)q, (const float4*)k, (const float4*)v,
      (ushort4*)qx, (ushort4*)kx, (ushort4*)vx);
  wt_cvt4<<<dim3(16, 16, 4), 256, 0, stream>>>(Wq, Wk, Wv, Wo,
                                               Wqt, Wkt, Wvt, Woth);

  gemm_qkv<<<768, 512, 0, stream>>>(qx, kx, vx, Wqt, Wkt, Wvt,
                                    bq, bk, bv, Qbf, Kbf, Vtb);

  attn_sums<<<512, 512, 0, stream>>>(Qbf, Kbf, mask, sums);
  attn_pv  <<<512, 512, 0, stream>>>(Qbf, Kbf, Vtb, mask, sums, attn, Ohb);

  gemm_fin64<<<512, 512, 0, stream>>>(Ohb, Woth, bo, out);
}

// Round 11
// 283.460 us; speedup vs baseline: 1.2252x; 1.2252x over previous
//
#include <hip/hip_runtime.h>
#include <hip/hip_bf16.h>
#include <math.h>

#define D_MODEL 1024
#define SEQ     2048
#define NHEAD   16

typedef __attribute__((ext_vector_type(8))) short bf16x8;
typedef __attribute__((ext_vector_type(8))) unsigned short u16x8;
typedef __attribute__((ext_vector_type(4))) float f32x4;
typedef const __attribute__((address_space(1))) unsigned int* gas_u32p;
typedef __attribute__((address_space(3))) unsigned int* las_u32p;

__device__ __forceinline__ void load16(const void* g, void* l) {
  __builtin_amdgcn_global_load_lds((gas_u32p)g, (las_u32p)l, 16, 0, 0);
}

__device__ __forceinline__ unsigned short f2bf(float f) {
  __hip_bfloat16 h = __float2bfloat16(f);
  return *(unsigned short*)&h;
}
__device__ __forceinline__ float bf2f(unsigned short u) {
  return __uint_as_float((unsigned)u << 16);
}

// ---------------------------------------------------------------------------
// fp32 -> bf16 for q,k,v in one launch (blockIdx.y selects tensor)
// ---------------------------------------------------------------------------
__global__ __launch_bounds__(256) void cvt3_bf16(
    const float4* __restrict__ q, const float4* __restrict__ k,
    const float4* __restrict__ v, ushort4* __restrict__ qo,
    ushort4* __restrict__ ko, ushort4* __restrict__ vo) {
  const int i = blockIdx.x * 256 + threadIdx.x;
  const float4* in = (blockIdx.y == 0) ? q : (blockIdx.y == 1) ? k : v;
  ushort4* out = (blockIdx.y == 0) ? qo : (blockIdx.y == 1) ? ko : vo;
  const float4 f = in[i];
  ushort4 u;
  u.x = f2bf(f.x); u.y = f2bf(f.y); u.z = f2bf(f.z); u.w = f2bf(f.w);
  out[i] = u;
}

// ---------------------------------------------------------------------------
// 4 x (W [1024 k][1024 n] fp32 -> Wt bf16 [n][k]), blockIdx.z selects
// ---------------------------------------------------------------------------
__global__ __launch_bounds__(256) void wt_cvt4(
    const float* __restrict__ W0, const float* __restrict__ W1,
    const float* __restrict__ W2, const float* __restrict__ W3,
    unsigned short* __restrict__ O0, unsigned short* __restrict__ O1,
    unsigned short* __restrict__ O2, unsigned short* __restrict__ O3) {
  __shared__ float t[64][65];
  const int z = blockIdx.z;
  const float* W = (z == 0) ? W0 : (z == 1) ? W1 : (z == 2) ? W2 : W3;
  unsigned short* Wh = (z == 0) ? O0 : (z == 1) ? O1 : (z == 2) ? O2 : O3;
  const int tid = threadIdx.x;
  const int k0 = blockIdx.y * 64, n0 = blockIdx.x * 64;
  #pragma unroll
  for (int it = 0; it < 4; ++it) {
    const int r = it * 16 + (tid >> 4), c4 = (tid & 15) * 4;
    const float4 f = *(const float4*)&W[(size_t)(k0 + r) * D_MODEL + n0 + c4];
    t[r][c4 + 0] = f.x; t[r][c4 + 1] = f.y;
    t[r][c4 + 2] = f.z; t[r][c4 + 3] = f.w;
  }
  __syncthreads();
  #pragma unroll
  for (int it = 0; it < 4; ++it) {
    const int n = it * 16 + (tid >> 4), k4 = (tid & 15) * 4;
    ushort4 uh;
    uh.x = f2bf(t[k4 + 0][n]); uh.y = f2bf(t[k4 + 1][n]);
    uh.z = f2bf(t[k4 + 2][n]); uh.w = f2bf(t[k4 + 3][n]);
    *(ushort4*)&Wh[(size_t)(n0 + n) * D_MODEL + k0 + k4] = uh;
  }
}

// ---------------------------------------------------------------------------
// Fused Q/K/V projections. 128x128 tile, BK=64, grid 768 (validated r7-r9).
// Q pre-scaled by 0.125*log2(e).
// ---------------------------------------------------------------------------
__global__ __launch_bounds__(512, 4) void gemm_qkv(
    const unsigned short* __restrict__ qx, const unsigned short* __restrict__ kx,
    const unsigned short* __restrict__ vx,
    const unsigned short* __restrict__ Wqt, const unsigned short* __restrict__ Wkt,
    const unsigned short* __restrict__ Wvt,
    const float* __restrict__ bq, const float* __restrict__ bk,
    const float* __restrict__ bv,
    unsigned short* __restrict__ Qo, unsigned short* __restrict__ Ko,
    unsigned short* __restrict__ Vto) {
  __shared__ char lds[65536];
  const int tid = threadIdx.x;
  const int lane = tid & 63, wid = tid >> 6;
  const int r16 = lane & 15, g = lane >> 4;
  const int bid = blockIdx.x;
  const int orig = (bid & 7) * 96 + (bid >> 3);
  const int which = orig >> 8;
  const int sub = orig & 255;
  const int bm = sub >> 3, bn = sub & 7;
  const int row0 = bm * 128, col0 = bn * 128;
  const int wm = wid >> 2, wn = wid & 3;

  const unsigned short* A = (which == 0) ? qx : (which == 1) ? kx : vx;
  const unsigned short* W = (which == 0) ? Wqt : (which == 1) ? Wkt : Wvt;
  const float* bias = (which == 0) ? bq : (which == 1) ? bk : bv;

  const unsigned short* Ag = A + (size_t)row0 * D_MODEL;
  const unsigned short* Bg = W + (size_t)col0 * D_MODEL;

  auto stage = [&](int buf, int k0) {
    char* base = lds + buf * 32768;
    #pragma unroll
    for (int c = 0; c < 2; ++c) {
      const int idx = c * 512 + tid;
      const int r = idx >> 3, ch = idx & 7;
      const size_t off = (size_t)r * D_MODEL + k0 + ((ch ^ (r & 7)) << 3);
      load16(Ag + off, base + idx * 16);
      load16(Bg + off, base + 16384 + idx * 16);
    }
  };

  stage(0, 0);
  f32x4 acc[4][2] = {};

  for (int s = 0; s < 16; ++s) {
    __syncthreads();
    if (s < 15) stage((s + 1) & 1, (s + 1) * 64);
    const char* base = lds + (s & 1) * 32768;
    #pragma unroll
    for (int kk = 0; kk < 2; ++kk) {
      bf16x8 a[4], b[2];
      #pragma unroll
      for (int mi = 0; mi < 4; ++mi) {
        const int r = wm * 64 + mi * 16 + r16;
        a[mi] = *(const bf16x8*)(base + r * 128 + (((g + kk * 4) ^ (r & 7)) << 4));
      }
      #pragma unroll
      for (int ni = 0; ni < 2; ++ni) {
        const int r = wn * 32 + ni * 16 + r16;
        b[ni] = *(const bf16x8*)(base + 16384 + r * 128 +
                                 (((g + kk * 4) ^ (r & 7)) << 4));
      }
      #pragma unroll
      for (int mi = 0; mi < 4; ++mi)
        #pragma unroll
        for (int ni = 0; ni < 2; ++ni)
          acc[mi][ni] = __builtin_amdgcn_mfma_f32_16x16x32_bf16(
              a[mi], b[ni], acc[mi][ni], 0, 0, 0);
    }
  }

  if (which < 2) {
    unsigned short* C = (which == 0) ? Qo : Ko;
    const float scale = (which == 0) ? 0.1803368802f : 1.0f;
    #pragma unroll
    for (int mi = 0; mi < 4; ++mi)
      #pragma unroll
      for (int ni = 0; ni < 2; ++ni) {
        const int col = col0 + wn * 32 + ni * 16 + r16;
        const float bb = bias[col];
        const int rowb = row0 + wm * 64 + mi * 16 + g * 4;
        #pragma unroll
        for (int j = 0; j < 4; ++j)
          C[(size_t)(rowb + j) * D_MODEL + col] =
              f2bf((acc[mi][ni][j] + bb) * scale);
      }
  } else {
    #pragma unroll
    for (int mi = 0; mi < 4; ++mi)
      #pragma unroll
      for (int ni = 0; ni < 2; ++ni) {
        const int col = col0 + wn * 32 + ni * 16 + r16;
        const int hh = col >> 6, dd = col & 63;
        const float bb = bias[col];
        const int rowb = row0 + wm * 64 + mi * 16 + g * 4;
        const int b_ = rowb >> 11, tt = rowb & 2047;
        ushort4 u;
        u.x = f2bf(acc[mi][ni][0] + bb);
        u.y = f2bf(acc[mi][ni][1] + bb);
        u.z = f2bf(acc[mi][ni][2] + bb);
        u.w = f2bf(acc[mi][ni][3] + bb);
        *(ushort4*)&Vto[((size_t)((b_ * NHEAD + hh) * 64 + dd)) * SEQ + tt] = u;
      }
  }
}

// ---------------------------------------------------------------------------
// Final GEMM: out = Oh @ Wh + bias, fp32. 64x128 tile, BK=64, grid 512
// (2-3 blocks/CU; ran correct in round 10).
// ---------------------------------------------------------------------------
__global__ __launch_bounds__(512, 4) void gemm_fin64(
    const unsigned short* __restrict__ A, const unsigned short* __restrict__ B,
    const float* __restrict__ bias, float* __restrict__ O) {
  __shared__ char lds[49152];                 // 2 x (8K A + 16K B)
  const int tid = threadIdx.x;
  const int lane = tid & 63, wid = tid >> 6;
  const int r16 = lane & 15, g = lane >> 4;
  const int bid = blockIdx.x;
  const int orig = (bid & 7) * 64 + (bid >> 3);   // XCD swizzle (512%8==0)
  const int bm = orig >> 3, bn = orig & 7;
  const int row0 = bm * 64, col0 = bn * 128;
  const int wm = wid >> 2, wn = wid & 3;          // 2(m) x 4(n)

  const unsigned short* Ag = A + (size_t)row0 * D_MODEL;
  const unsigned short* Bg = B + (size_t)col0 * D_MODEL;

  auto stage = [&](int buf, int k0) {
    char* base = lds + buf * 24576;
    {                                          // A: 64 rows x 64 k
      const int r = tid >> 3, ch = tid & 7;
      load16(Ag + (size_t)r * D_MODEL + k0 + ((ch ^ (r & 7)) << 3),
             base + tid * 16);
    }
    #pragma unroll
    for (int c = 0; c < 2; ++c) {              // B: 128 rows x 64 k
      const int idx = c * 512 + tid;
      const int r = idx >> 3, ch = idx & 7;
      load16(Bg + (size_t)r * D_MODEL + k0 + ((ch ^ (r & 7)) << 3),
             base + 8192 + idx * 16);
    }
  };

  stage(0, 0);
  f32x4 acc[2][2] = {};

  for (int s = 0; s < 16; ++s) {
    __syncthreads();
    if (s < 15) stage((s + 1) & 1, (s + 1) * 64);
    const char* base = lds + (s & 1) * 24576;
    #pragma unroll
    for (int kk = 0; kk < 2; ++kk) {
      bf16x8 a[2], b[2];
      #pragma unroll
      for (int mi = 0; mi < 2; ++mi) {
        const int r = wm * 32 + mi * 16 + r16;
        a[mi] = *(const bf16x8*)(base + r * 128 + (((g + kk * 4) ^ (r & 7)) << 4));
      }
      #pragma unroll
      for (int ni = 0; ni < 2; ++ni) {
        const int r = wn * 32 + ni * 16 + r16;
        b[ni] = *(const bf16x8*)(base + 8192 + r * 128 +
                                 (((g + kk * 4) ^ (r & 7)) << 4));
      }
      #pragma unroll
      for (int mi = 0; mi < 2; ++mi)
        #pragma unroll
        for (int ni = 0; ni < 2; ++ni)
          acc[mi][ni] = __builtin_amdgcn_mfma_f32_16x16x32_bf16(
              a[mi], b[ni], acc[mi][ni], 0, 0, 0);
    }
  }

  #pragma unroll
  for (int mi = 0; mi < 2; ++mi)
    #pragma unroll
    for (int ni = 0; ni < 2; ++ni) {
      const int col = col0 + wn * 32 + ni * 16 + r16;
      const float bb = bias[col];
      const int rowb = row0 + wm * 32 + mi * 16 + g * 4;
      #pragma unroll
      for (int j = 0; j < 4; ++j)
        O[(size_t)(rowb + j) * D_MODEL + col] = acc[mi][ni][j] + bb;
    }
}

// ---------------------------------------------------------------------------
// Two-pass MFMA attention, QB=64 — round-9 validated form, byte-identical.
// (two barriers/iter, ring-4 K + ring-4 V, 3-deep prefetch, vmcnt(10);
//  exp2 with Q pre-scaled by log2e; O epilogue bf16 hi only.)
// ---------------------------------------------------------------------------
__global__ __launch_bounds__(512, 4) void attn_2pass(
    const unsigned short* __restrict__ Qb,   // bf16, pre-scaled 0.125*log2e
    const unsigned short* __restrict__ Kb,   // bf16 [4096][1024]
    const unsigned short* __restrict__ Vt,   // bf16 [32*64][2048]
    const int* __restrict__ mask,            // [2][2048]
    float* __restrict__ attn,                // [32][2048][2048]
    unsigned short* __restrict__ Oh) {       // bf16 [4096][1024]
  __shared__ char lds[74752];
  char* const Kbuf = lds;                    // 4 x 8192
  char* const Vbuf = lds + 32768;            // 4 x 8192 (slot0 = Q staging)
  char* const Pt   = lds + 65536;            // 8192: P tile 64x64 bf16
  float* const red = (float*)(lds + 73728);  // [4 wt][64 q]

  const int tid  = threadIdx.x;
  const int lane = tid & 63;
  const int wid  = tid >> 6;
  const int r16  = lane & 15;
  const int g    = lane >> 4;
  const int wq2  = wid >> 2;
  const int wt   = wid & 3;

  const int bid  = blockIdx.x;
  const int orig = (bid & 7) * 128 + (bid >> 3);   // XCD swizzle (1024%8==0)
  const int bh   = orig >> 5;
  const int qblk = orig & 31;
  const int b    = bh >> 4, h = bh & 15;
  const int q0   = qblk * 64;

  const unsigned short* Kg0 = Kb + (size_t)(b * SEQ) * D_MODEL + h * 64;
  const unsigned short* Qg0 = Qb + (size_t)(b * SEQ + q0) * D_MODEL + h * 64;
  const unsigned short* Vg0 = Vt + (size_t)(bh * 64) * SEQ;
  const int* mrow = mask + b * SEQ;

  const int srow = tid >> 3, sch = tid & 7;
  const int ssw  = srow & 7;

  auto stageK = [&](int t) {
    load16((const char*)(Kg0 + (size_t)(t * 64 + srow) * D_MODEL) +
               ((sch ^ ssw) << 4),
           Kbuf + ((t & 3) << 13) + tid * 16);
  };
  auto stageV = [&](int t) {
    load16((const char*)(Vg0 + (size_t)srow * SEQ + t * 64) +
               ((sch ^ ssw) << 4),
           Vbuf + ((t & 3) << 13) + tid * 16);
  };

  // per-lane mask bits for t = i*64 + wt*16 + r16 (consumed before staging)
  const int tb = wt * 16 + r16;
  unsigned mbits = 0;
  #pragma unroll 4
  for (int i = 0; i < 32; ++i)
    mbits |= (mrow[i * 64 + tb] ? 1u : 0u) << i;
  asm volatile("s_waitcnt vmcnt(0)" ::: "memory");  // clean FIFO before staging

  // ---- prologue: Q into Vbuf slot0, K tiles 0..2 -------------------------
  load16((const char*)(Qg0 + (size_t)srow * D_MODEL) + ((sch ^ ssw) << 4),
         Vbuf + tid * 16);
  stageK(0); stageK(1); stageK(2);
  asm volatile("s_waitcnt vmcnt(3)\n\ts_barrier" ::: "memory");  // Q resident

  bf16x8 qa[2][2];
  #pragma unroll
  for (int f = 0; f < 2; ++f) {
    const int row = wq2 * 32 + f * 16 + r16;
    const int sw = (row & 7) << 4;
    qa[f][0] = *(const bf16x8*)(Vbuf + row * 128 + ((g * 16) ^ sw));
    qa[f][1] = *(const bf16x8*)(Vbuf + row * 128 + ((g * 16 + 64) ^ sw));
  }

  const int krow = wt * 16 + r16;
  const int ksw  = (krow & 7) << 4;

  // ---- pass 1: rowsums ---------------------------------------------------
  float rs[2][4] = {};
  for (int i = 0; i < 32; ++i) {
    if (i < 30)
      asm volatile("s_waitcnt vmcnt(2)\n\ts_barrier" ::: "memory");
    else if (i == 30)
      asm volatile("s_waitcnt vmcnt(1)\n\ts_barrier" ::: "memory");
    else
      asm volatile("s_waitcnt vmcnt(0)\n\ts_barrier" ::: "memory");
    if (i + 3 < 32) stageK(i + 3);
    const char* Kt = Kbuf + ((i & 3) << 13);
    const bf16x8 kb0 = *(const bf16x8*)(Kt + krow * 128 + ((g * 16) ^ ksw));
    const bf16x8 kb1 = *(const bf16x8*)(Kt + krow * 128 + ((g * 16 + 64) ^ ksw));
    f32x4 c0 = {0.f, 0.f, 0.f, 0.f}, c1 = {0.f, 0.f, 0.f, 0.f};
    __builtin_amdgcn_s_setprio(1);
    c0 = __builtin_amdgcn_mfma_f32_16x16x32_bf16(qa[0][0], kb0, c0, 0, 0, 0);
    c0 = __builtin_amdgcn_mfma_f32_16x16x32_bf16(qa[0][1], kb1, c0, 0, 0, 0);
    c1 = __builtin_amdgcn_mfma_f32_16x16x32_bf16(qa[1][0], kb0, c1, 0, 0, 0);
    c1 = __builtin_amdgcn_mfma_f32_16x16x32_bf16(qa[1][1], kb1, c1, 0, 0, 0);
    __builtin_amdgcn_s_setprio(0);
    if (!((mbits >> i) & 1u)) {
      rs[0][0] += exp2f(c0[0]); rs[0][1] += exp2f(c0[1]);
      rs[0][2] += exp2f(c0[2]); rs[0][3] += exp2f(c0[3]);
      rs[1][0] += exp2f(c1[0]); rs[1][1] += exp2f(c1[1]);
      rs[1][2] += exp2f(c1[2]); rs[1][3] += exp2f(c1[3]);
    }
  }

  // ---- rowsum reduction (16-lane groups share a q-frag row set) ----------
  #pragma unroll
  for (int f = 0; f < 2; ++f)
    #pragma unroll
    for (int j = 0; j < 4; ++j) {
      float v = rs[f][j];
      v += __shfl_xor(v, 1); v += __shfl_xor(v, 2);
      v += __shfl_xor(v, 4); v += __shfl_xor(v, 8);
      rs[f][j] = v;
    }
  if (r16 == 0) {
    #pragma unroll
    for (int f = 0; f < 2; ++f)
      #pragma unroll
      for (int j = 0; j < 4; ++j)
        red[wt * 64 + wq2 * 32 + f * 16 + g * 4 + j] = rs[f][j];
  }
  __syncthreads();

  float inv_[2][4];
  #pragma unroll
  for (int f = 0; f < 2; ++f)
    #pragma unroll
    for (int j = 0; j < 4; ++j) {
      const int row = wq2 * 32 + f * 16 + g * 4 + j;
      inv_[f][j] = 1.f / (red[0 * 64 + row] + red[1 * 64 + row] +
                          red[2 * 64 + row] + red[3 * 64 + row]);
    }

  // ---- pass 2 prologue ---------------------------------------------------
  stageK(0); stageV(0); stageK(1); stageV(1); stageK(2); stageV(2);

  f32x4 o0 = {0.f, 0.f, 0.f, 0.f}, o1 = {0.f, 0.f, 0.f, 0.f};
  // readback mapping: thread -> q row tid>>3, 8 cols at (tid&7)*8
  const int rbq = tid >> 3, rbc8 = (tid & 7) * 8;
  const int rboff = (rbq * 128 + rbc8 * 2) ^ ((rbq & 7) << 4);
  float* const aT = attn + ((size_t)bh * SEQ + q0 + rbq) * SEQ + rbc8;

  for (int i = 0; i < 32; ++i) {
    // FIFO (2 loads + 2 stores/iter, 3-deep prefetch): 4,6,8,10..10,8,6
    if (i >= 3 && i <= 29)
      asm volatile("s_waitcnt vmcnt(10)\n\ts_barrier" ::: "memory");
    else if (i == 2 || i == 30)
      asm volatile("s_waitcnt vmcnt(8)\n\ts_barrier" ::: "memory");
    else if (i == 1 || i == 31)
      asm volatile("s_waitcnt vmcnt(6)\n\ts_barrier" ::: "memory");
    else
      asm volatile("s_waitcnt vmcnt(4)\n\ts_barrier" ::: "memory");
    if (i + 3 < 32) { stageK(i + 3); stageV(i + 3); }

    const char* Kt = Kbuf + ((i & 3) << 13);
    const bf16x8 kb0 = *(const bf16x8*)(Kt + krow * 128 + ((g * 16) ^ ksw));
    const bf16x8 kb1 = *(const bf16x8*)(Kt + krow * 128 + ((g * 16 + 64) ^ ksw));
    f32x4 c0 = {0.f, 0.f, 0.f, 0.f}, c1 = {0.f, 0.f, 0.f, 0.f};
    __builtin_amdgcn_s_setprio(1);
    c0 = __builtin_amdgcn_mfma_f32_16x16x32_bf16(qa[0][0], kb0, c0, 0, 0, 0);
    c0 = __builtin_amdgcn_mfma_f32_16x16x32_bf16(qa[0][1], kb1, c0, 0, 0, 0);
    c1 = __builtin_amdgcn_mfma_f32_16x16x32_bf16(qa[1][0], kb0, c1, 0, 0, 0);
    c1 = __builtin_amdgcn_mfma_f32_16x16x32_bf16(qa[1][1], kb1, c1, 0, 0, 0);
    __builtin_amdgcn_s_setprio(0);

    const unsigned mk = (mbits >> i) & 1u;
    float p[2][4];
    p[0][0] = mk ? 0.f : exp2f(c0[0]) * inv_[0][0];
    p[0][1] = mk ? 0.f : exp2f(c0[1]) * inv_[0][1];
    p[0][2] = mk ? 0.f : exp2f(c0[2]) * inv_[0][2];
    p[0][3] = mk ? 0.f : exp2f(c0[3]) * inv_[0][3];
    p[1][0] = mk ? 0.f : exp2f(c1[0]) * inv_[1][0];
    p[1][1] = mk ? 0.f : exp2f(c1[1]) * inv_[1][1];
    p[1][2] = mk ? 0.f : exp2f(c1[2]) * inv_[1][2];
    p[1][3] = mk ? 0.f : exp2f(c1[3]) * inv_[1][3];

    #pragma unroll
    for (int f = 0; f < 2; ++f)
      #pragma unroll
      for (int j = 0; j < 4; ++j) {
        const int row = wq2 * 32 + f * 16 + g * 4 + j;
        *(unsigned short*)(Pt + ((row * 128 + tb * 2) ^ ((row & 7) << 4))) =
            f2bf(p[f][j]);
      }

    asm volatile("s_waitcnt lgkmcnt(0)\n\ts_barrier" ::: "memory");

    const char* Vtl = Vbuf + ((i & 3) << 13);
    const bf16x8 vb0 = *(const bf16x8*)(Vtl + krow * 128 + ((g * 16) ^ ksw));
    const bf16x8 vb1 = *(const bf16x8*)(Vtl + krow * 128 + ((g * 16 + 64) ^ ksw));
    {
      const int pr0 = wq2 * 32 + r16;
      const int psw0 = (pr0 & 7) << 4;
      const bf16x8 pa0 = *(const bf16x8*)(Pt + pr0 * 128 + ((g * 16) ^ psw0));
      const bf16x8 pa1 = *(const bf16x8*)(Pt + pr0 * 128 + ((g * 16 + 64) ^ psw0));
      const int pr1 = pr0 + 16;
      const int psw1 = (pr1 & 7) << 4;
      const bf16x8 pb0 = *(const bf16x8*)(Pt + pr1 * 128 + ((g * 16) ^ psw1));
      const bf16x8 pb1 = *(const bf16x8*)(Pt + pr1 * 128 + ((g * 16 + 64) ^ psw1));
      __builtin_amdgcn_s_setprio(1);
      o0 = __builtin_amdgcn_mfma_f32_16x16x32_bf16(pa0, vb0, o0, 0, 0, 0);
      o0 = __builtin_amdgcn_mfma_f32_16x16x32_bf16(pa1, vb1, o0, 0, 0, 0);
      o1 = __builtin_amdgcn_mfma_f32_16x16x32_bf16(pb0, vb0, o1, 0, 0, 0);
      o1 = __builtin_amdgcn_mfma_f32_16x16x32_bf16(pb1, vb1, o1, 0, 0, 0);
      __builtin_amdgcn_s_setprio(0);
    }

    // coalesced attn write: u16x8 LDS readback -> 2 float4 stores
    {
      const u16x8 pv = *(const u16x8*)(Pt + rboff);
      float4 oA, oB;
      oA.x = bf2f(pv[0]); oA.y = bf2f(pv[1]);
      oA.z = bf2f(pv[2]); oA.w = bf2f(pv[3]);
      oB.x = bf2f(pv[4]); oB.y = bf2f(pv[5]);
      oB.z = bf2f(pv[6]); oB.w = bf2f(pv[7]);
      *(float4*)(aT + (size_t)i * 64) = oA;
      *(float4*)(aT + (size_t)i * 64 + 4) = oB;
    }
  }

  // ---- O epilogue (normalized), bf16 -------------------------------------
  #pragma unroll
  for (int f = 0; f < 2; ++f)
    #pragma unroll
    for (int j = 0; j < 4; ++j) {
      const int row = q0 + wq2 * 32 + f * 16 + g * 4 + j;
      const size_t idx = (size_t)(b * SEQ + row) * D_MODEL + h * 64 + wt * 16 + r16;
      Oh[idx] = f2bf(f ? o1[j] : o0[j]);
    }
}

// ---------------------------------------------------------------------------
extern "C" void kernel_launch(void* const* d_in, const int* in_sizes, int n_in,
                              void* d_out, int out_size, void* d_ws, size_t ws_size,
                              hipStream_t stream) {
  const float* v    = (const float*)d_in[0];
  const float* k    = (const float*)d_in[1];
  const float* q    = (const float*)d_in[2];
  const int*   mask = (const int*)  d_in[3];
  const float* Wq   = (const float*)d_in[4];
  const float* bq   = (const float*)d_in[5];
  const float* Wk   = (const float*)d_in[6];
  const float* bk   = (const float*)d_in[7];
  const float* Wv   = (const float*)d_in[8];
  const float* bv   = (const float*)d_in[9];
  const float* Wo   = (const float*)d_in[10];
  const float* bo   = (const float*)d_in[11];

  const size_t NTOK = (size_t)2 * SEQ;            // 4096 tokens
  const size_t TOKF = NTOK * D_MODEL;             // 4,194,304 elements
  const size_t WSZ  = (size_t)D_MODEL * D_MODEL;  // 1,048,576
  float* out  = (float*)d_out;
  float* attn = out + TOKF;

  unsigned short* qx   = (unsigned short*)d_ws;   // bf16 inputs
  unsigned short* kx   = qx + TOKF;
  unsigned short* vx   = kx + TOKF;
  unsigned short* Qbf  = vx + TOKF;               // projections
  unsigned short* Kbf  = Qbf + TOKF;
  unsigned short* Vtb  = Kbf + TOKF;
  unsigned short* Ohb  = Vtb + TOKF;              // attn O (bf16)
  unsigned short* Wqt  = Ohb + TOKF;              // transposed bf16 weights
  unsigned short* Wkt  = Wqt + WSZ;
  unsigned short* Wvt  = Wkt + WSZ;
  unsigned short* Woth = Wvt + WSZ;

  const int cvtg = (int)(TOKF / 4 / 256);         // 4096 blocks
  cvt3_bf16<<<dim3(cvtg, 3), 256, 0, stream>>>(
      (const float4*)q, (const float4*)k, (const float4*)v,
      (ushort4*)qx, (ushort4*)kx, (ushort4*)vx);
  wt_cvt4<<<dim3(16, 16, 4), 256, 0, stream>>>(Wq, Wk, Wv, Wo,
                                               Wqt, Wkt, Wvt, Woth);

  gemm_qkv<<<768, 512, 0, stream>>>(qx, kx, vx, Wqt, Wkt, Wvt,
                                    bq, bk, bv, Qbf, Kbf, Vtb);

  attn_2pass<<<1024, 512, 0, stream>>>(Qbf, Kbf, Vtb, mask, attn, Ohb);

  gemm_fin64<<<512, 512, 0, stream>>>(Ohb, Woth, bo, out);
}